// Round 13
// baseline (563.401 us; speedup 1.0000x reference)
//
#include <hip/hip_runtime.h>
#include <hip/hip_cooperative_groups.h>
#include <float.h>

namespace cg = cooperative_groups;

// Problem constants (match reference)
#define BSX 2.0f
#define BSY 2.0f
#define NBX 512
#define NBY 512
#define MAX_SPAN 4
#define TINY 1.17549435e-38f   // np.finfo(float32).tiny

// ---- Tiled path parameters ----
#define TSB 5                  // log2(tile size in bins): 32x32 bins = 64x64 units
#define TS  32
#define NTT 16                 // tiles per axis (512/32)
#define NTILES 256
#define BTH 256
#define NPT 4                  // nets per thread
#define NPB (BTH * NPT)        // nets per block = 1024
#define CSTRIDE 32             // cursor padding: one 128B line per counter
#define G 8                    // cursor/list shards per tile
#define SEG 1024               // entries per (tile,shard) segment (mean ~537, +21 sigma)
#define CBLK 1024              // cooperative grid (4 blocks/CU on 256 CUs)

#define FP_SCALE 4194304.0f    // 2^22 (validated r2/r5)
#define FP_INV   (1.0f / 4194304.0f)

typedef unsigned int u32;
typedef unsigned long long ull;

// Entry (16B): x: x0q(1/1024)|dxq(1/16384)<<16; y likewise; z/w: premult weights.

// Shared PROCESS body for the accumulate phases
#define PROCESS_ENTRY(COND, PP, SHV)                                            \
    if (COND) {                                                                 \
        uint4 p = (PP);                                                         \
        float x0 = (float)(p.x & 0xFFFFu) * (1.0f / 1024.0f);                   \
        float x1 = x0 + (float)(p.x >> 16) * (1.0f / 16384.0f);                 \
        float y0 = (float)(p.y & 0xFFFFu) * (1.0f / 1024.0f);                   \
        float y1 = y0 + (float)(p.y >> 16) * (1.0f / 16384.0f);                 \
        float wh = __uint_as_float(p.z);                                        \
        float wv = __uint_as_float(p.w);                                        \
        int rxl = min((int)(x0 * 0.5f), TS - 1);                                \
        int rxh = min((int)(x1 * 0.5f) + 1, TS);                                \
        int ryl = min((int)(y0 * 0.5f), TS - 1);                                \
        int ryh = min((int)(y1 * 0.5f) + 1, TS);                                \
        for (int bx = rxl; bx < rxh; ++bx) {                                    \
            float bl = (float)bx * BSX;                                         \
            float ox = fmaxf(fminf(x1, bl + BSX) - fmaxf(x0, bl), 0.0f);        \
            float oxh = ox * wh * FP_SCALE, oxv = ox * wv * FP_SCALE;           \
            int rowbase = bx * TS;                                              \
            for (int by = ryl; by < ryh; ++by) {                                \
                float bb = (float)by * BSY;                                     \
                float oy = fmaxf(fminf(y1, bb + BSY) - fmaxf(y0, bb), 0.0f);    \
                u32 hq = (u32)(oxh * oy + 0.5f);                                \
                u32 vq = (u32)(oxv * oy + 0.5f);                                \
                ull pk = ((ull)hq << 32) | (ull)vq;                             \
                atomicAdd(&(SHV)[rowbase + by], pk);                            \
            }                                                                   \
        }                                                                       \
    }

// ==================== single-dispatch cooperative kernel ====================

__global__ __launch_bounds__(256, 4) void rudy_fused(
    const float* __restrict__ pin_pos,
    const float* __restrict__ net_weights,
    const int*   __restrict__ netpin_start,
    const int*   __restrict__ flat_netpin,
    u32*         __restrict__ cursor,     // [NTILES*G] padded by CSTRIDE
    uint4*       __restrict__ list,       // [NTILES*G][SEG]
    ull*         __restrict__ partial,    // [CBLK][TS*TS]
    float*       __restrict__ out,
    int num_nets, int n_total)
{
    cg::grid_group grid = cg::this_grid();

    __shared__ ull shv[TS * TS];          // 8 KB; aliased as u32[2048] for bin phase
    u32* s32 = (u32*)shv;                 // s_cnt = s32[0..255], s_fill = s32[256..511]

    int tid = threadIdx.x;
    int b   = blockIdx.x;
    int gidx = b * BTH + tid;

    // ---- Phase A: init sharded cursors ----
    if (gidx < NTILES * G) cursor[(u32)gidx * CSTRIDE] = 0u;
    __threadfence();
    grid.sync();

    // ---- Phase B: bin (r12 structure; blocks beyond net range idle) ----
    {
        int g = b & (G - 1);
        s32[tid] = 0u; s32[BTH + tid] = 0u;
        __syncthreads();

        int bs = b * NPB;

        int sA[NPT], eA[NPT];
        #pragma unroll
        for (int k = 0; k < NPT; ++k) {
            sA[k] = 0; eA[k] = 0;
            int i = bs + k * BTH + tid;
            if (i < num_nets) { sA[k] = netpin_start[i]; eA[k] = netpin_start[i + 1]; }
        }
        int4 fA[NPT];
        #pragma unroll
        for (int k = 0; k < NPT; ++k) {
            fA[k] = make_int4(-1, -1, -1, -1);
            if (eA[k] - sA[k] == 4 && (sA[k] & 3) == 0)
                fA[k] = *(const int4*)(flat_netpin + sA[k]);
        }
        bool idA[NPT];
        float4 xvA[NPT], yvA[NPT];
        #pragma unroll
        for (int k = 0; k < NPT; ++k) {
            int s = sA[k];
            idA[k] = (fA[k].x == s && fA[k].y == s + 1 && fA[k].z == s + 2 && fA[k].w == s + 3);
            if (idA[k]) {
                xvA[k] = *(const float4*)(pin_pos + s);
                yvA[k] = *(const float4*)(pin_pos + s + n_total);
            }
        }
        float wgt[NPT];
        #pragma unroll
        for (int k = 0; k < NPT; ++k) {
            int i = bs + k * BTH + tid;
            wgt[k] = (i < num_nets) ? net_weights[i] : 0.0f;
        }

        float fx0[NPT], fx1[NPT], fy0[NPT], fy1[NPT], fwh[NPT], fwv[NPT];
        u32 trng[NPT];

        #pragma unroll
        for (int k = 0; k < NPT; ++k) {
            trng[k] = 0x00000001u;
            fx0[k] = 0.f; fx1[k] = 0.f; fy0[k] = 0.f; fy1[k] = 0.f;
            fwh[k] = 0.f; fwv[k] = 0.f;
            int i = bs + k * BTH + tid;
            if (i < num_nets) {
                bool have = false;
                float xmin, xmax, ymin, ymax;
                if (idA[k]) {
                    xmin = fminf(fminf(xvA[k].x, xvA[k].y), fminf(xvA[k].z, xvA[k].w));
                    xmax = fmaxf(fmaxf(xvA[k].x, xvA[k].y), fmaxf(xvA[k].z, xvA[k].w));
                    ymin = fminf(fminf(yvA[k].x, yvA[k].y), fminf(yvA[k].z, yvA[k].w));
                    ymax = fmaxf(fmaxf(yvA[k].x, yvA[k].y), fmaxf(yvA[k].z, yvA[k].w));
                    have = true;
                } else if (eA[k] > sA[k]) {
                    xmin = FLT_MAX; xmax = -FLT_MAX; ymin = FLT_MAX; ymax = -FLT_MAX;
                    for (int p = sA[k]; p < eA[k]; ++p) {
                        int idx = flat_netpin[p];
                        float x = pin_pos[idx], y = pin_pos[idx + n_total];
                        xmin = fminf(xmin, x); xmax = fmaxf(xmax, x);
                        ymin = fminf(ymin, y); ymax = fmaxf(ymax, y);
                    }
                    have = true;
                }
                if (have) {
                    fx0[k] = xmin; fx1[k] = xmax; fy0[k] = ymin; fy1[k] = ymax;
                    fwh[k] = wgt[k] / (ymax - ymin + TINY);
                    fwv[k] = wgt[k] / (xmax - xmin + TINY);
                    int ixl = min(max((int)(xmin * 0.5f), 0), NBX - 1);
                    int ixh = min(min((int)(xmax * 0.5f) + 1, NBX), ixl + MAX_SPAN);
                    int iyl = min(max((int)(ymin * 0.5f), 0), NBY - 1);
                    int iyh = min(min((int)(ymax * 0.5f) + 1, NBY), iyl + MAX_SPAN);
                    int txl = ixl >> TSB, txh = (ixh - 1) >> TSB;
                    int tyl = iyl >> TSB, tyh = (iyh - 1) >> TSB;
                    trng[k] = (u32)txl | ((u32)txh << 8) | ((u32)tyl << 16) | ((u32)tyh << 24);
                    for (int tx = txl; tx <= txh; ++tx)
                        for (int ty = tyl; ty <= tyh; ++ty)
                            atomicAdd(&s32[tx * NTT + ty], 1u);
                }
            }
        }
        __syncthreads();

        // sharded global reserve
        {
            u32 c = s32[tid];
            u32 gbase = 0;
            if (c) gbase = atomicAdd(&cursor[((u32)tid * G + (u32)g) * CSTRIDE], c);
            s32[tid] = gbase;
        }
        __syncthreads();

        // direct-scatter emit
        #pragma unroll
        for (int k = 0; k < NPT; ++k) {
            u32 tr = trng[k];
            int txl = (int)(tr & 0xFFu), txh = (int)((tr >> 8) & 0xFFu);
            int tyl = (int)((tr >> 16) & 0xFFu), tyh = (int)(tr >> 24);
            for (int tx = txl; tx <= txh; ++tx) {
                float tox = (float)(tx << TSB) * BSX;
                float rx0 = fminf(fmaxf(fx0[k] - tox, 0.0f), 64.0f);
                float rx1 = fminf(fmaxf(fx1[k] - tox, 0.0f), 64.0f);
                u32 x0q = min((u32)(rx0 * 1024.0f + 0.5f), 65535u);
                u32 dxq = min((u32)((rx1 - rx0) * 16384.0f + 0.5f), 65535u);
                for (int ty = tyl; ty <= tyh; ++ty) {
                    float toy = (float)(ty << TSB) * BSY;
                    float ry0 = fminf(fmaxf(fy0[k] - toy, 0.0f), 64.0f);
                    float ry1 = fminf(fmaxf(fy1[k] - toy, 0.0f), 64.0f);
                    u32 y0q = min((u32)(ry0 * 1024.0f + 0.5f), 65535u);
                    u32 dyq = min((u32)((ry1 - ry0) * 16384.0f + 0.5f), 65535u);
                    int t = tx * NTT + ty;
                    uint4 pk;
                    pk.x = x0q | (dxq << 16);
                    pk.y = y0q | (dyq << 16);
                    pk.z = __float_as_uint(fwh[k]);
                    pk.w = __float_as_uint(fwv[k]);
                    u32 slot = atomicAdd(&s32[BTH + t], 1u);
                    u32 pos = s32[t] + slot;
                    if (pos < (u32)SEG)
                        list[(((size_t)t * G + (size_t)(b & (G - 1))) << 10) + pos] = pk;
                }
            }
        }
    }
    __threadfence();
    grid.sync();

    // ---- Phase C: accumulate 2 segments per block into LDS tile -> partial ----
    {
        #pragma unroll
        for (int j2 = 0; j2 < 4; ++j2) shv[tid + j2 * BTH] = 0ull;
        __syncthreads();

        int t = b >> 2;
        int jp = b & 3;
        u32 s0 = (u32)t * G + 2u * jp;
        u32 s1 = s0 + 1u;
        u32 n0 = min(cursor[s0 * CSTRIDE], (u32)SEG);
        u32 n1 = min(cursor[s1 * CSTRIDE], (u32)SEG);
        const uint4* base0 = list + ((size_t)s0 << 10);
        const uint4* base1 = list + ((size_t)s1 << 10);

        uint4 a0, a1, a2, a3, c0, c1, c2, c3;
        u32 q0 = tid, q1 = tid + 256u, q2 = tid + 512u, q3 = tid + 768u;
        if (q0 < n0) a0 = base0[q0];
        if (q1 < n0) a1 = base0[q1];
        if (q2 < n0) a2 = base0[q2];
        if (q3 < n0) a3 = base0[q3];
        if (q0 < n1) c0 = base1[q0];
        if (q1 < n1) c1 = base1[q1];
        if (q2 < n1) c2 = base1[q2];
        if (q3 < n1) c3 = base1[q3];

        PROCESS_ENTRY(q0 < n0, a0, shv)
        PROCESS_ENTRY(q1 < n0, a1, shv)
        PROCESS_ENTRY(q2 < n0, a2, shv)
        PROCESS_ENTRY(q3 < n0, a3, shv)
        PROCESS_ENTRY(q0 < n1, c0, shv)
        PROCESS_ENTRY(q1 < n1, c1, shv)
        PROCESS_ENTRY(q2 < n1, c2, shv)
        PROCESS_ENTRY(q3 < n1, c3, shv)

        __syncthreads();

        ull* dst = partial + ((size_t)b << 10);
        #pragma unroll
        for (int j2 = 0; j2 < 4; ++j2) dst[tid + j2 * BTH] = shv[tid + j2 * BTH];
    }
    __threadfence();
    grid.sync();

    // ---- Phase D: merge 4 partials per bin -> out (1 bin per thread) ----
    {
        int k = gidx;                 // CBLK*BTH == NBX*NBY == 262144
        int t2 = k >> 10;
        int q = k & 1023;
        const ull* p = partial + ((size_t)(t2 << 2) << 10) + q;
        ull s = p[0] + p[1 << 10] + p[2 << 10] + p[3 << 10];
        float h = (float)(u32)(s >> 32);
        float v = (float)(u32)(s & 0xFFFFFFFFull);
        int tx = t2 >> 4, ty = t2 & 15;
        int bx = q >> 5, by = q & 31;
        out[(size_t)(tx * TS + bx) * NBY + (ty * TS + by)] =
            fmaxf(h, v) * (FP_INV * (1.0f / 6.0f));
    }
}

// ==================== fallback 1: r12 three-kernel path ====================

__global__ __launch_bounds__(BTH) void bin_nets(
    const float* __restrict__ pin_pos,
    const float* __restrict__ net_weights,
    const int*   __restrict__ netpin_start,
    const int*   __restrict__ flat_netpin,
    u32*         __restrict__ cursor,
    uint4*       __restrict__ list,
    int num_nets, int n_total)
{
    __shared__ u32 s_cnt[NTILES];
    __shared__ u32 s_fill[NTILES];

    int tid = threadIdx.x;
    int g = blockIdx.x & (G - 1);
    s_cnt[tid] = 0u; s_fill[tid] = 0u;
    __syncthreads();

    int bs = blockIdx.x * NPB;

    int sA[NPT], eA[NPT];
    #pragma unroll
    for (int k = 0; k < NPT; ++k) {
        sA[k] = 0; eA[k] = 0;
        int i = bs + k * BTH + tid;
        if (i < num_nets) { sA[k] = netpin_start[i]; eA[k] = netpin_start[i + 1]; }
    }
    int4 fA[NPT];
    #pragma unroll
    for (int k = 0; k < NPT; ++k) {
        fA[k] = make_int4(-1, -1, -1, -1);
        if (eA[k] - sA[k] == 4 && (sA[k] & 3) == 0)
            fA[k] = *(const int4*)(flat_netpin + sA[k]);
    }
    bool idA[NPT];
    float4 xvA[NPT], yvA[NPT];
    #pragma unroll
    for (int k = 0; k < NPT; ++k) {
        int s = sA[k];
        idA[k] = (fA[k].x == s && fA[k].y == s + 1 && fA[k].z == s + 2 && fA[k].w == s + 3);
        if (idA[k]) {
            xvA[k] = *(const float4*)(pin_pos + s);
            yvA[k] = *(const float4*)(pin_pos + s + n_total);
        }
    }
    float wgt[NPT];
    #pragma unroll
    for (int k = 0; k < NPT; ++k) {
        int i = bs + k * BTH + tid;
        wgt[k] = (i < num_nets) ? net_weights[i] : 0.0f;
    }

    float fx0[NPT], fx1[NPT], fy0[NPT], fy1[NPT], fwh[NPT], fwv[NPT];
    u32 trng[NPT];

    #pragma unroll
    for (int k = 0; k < NPT; ++k) {
        trng[k] = 0x00000001u;
        fx0[k] = 0.f; fx1[k] = 0.f; fy0[k] = 0.f; fy1[k] = 0.f;
        fwh[k] = 0.f; fwv[k] = 0.f;
        int i = bs + k * BTH + tid;
        if (i < num_nets) {
            bool have = false;
            float xmin, xmax, ymin, ymax;
            if (idA[k]) {
                xmin = fminf(fminf(xvA[k].x, xvA[k].y), fminf(xvA[k].z, xvA[k].w));
                xmax = fmaxf(fmaxf(xvA[k].x, xvA[k].y), fmaxf(xvA[k].z, xvA[k].w));
                ymin = fminf(fminf(yvA[k].x, yvA[k].y), fminf(yvA[k].z, yvA[k].w));
                ymax = fmaxf(fmaxf(yvA[k].x, yvA[k].y), fmaxf(yvA[k].z, yvA[k].w));
                have = true;
            } else if (eA[k] > sA[k]) {
                xmin = FLT_MAX; xmax = -FLT_MAX; ymin = FLT_MAX; ymax = -FLT_MAX;
                for (int p = sA[k]; p < eA[k]; ++p) {
                    int idx = flat_netpin[p];
                    float x = pin_pos[idx], y = pin_pos[idx + n_total];
                    xmin = fminf(xmin, x); xmax = fmaxf(xmax, x);
                    ymin = fminf(ymin, y); ymax = fmaxf(ymax, y);
                }
                have = true;
            }
            if (have) {
                fx0[k] = xmin; fx1[k] = xmax; fy0[k] = ymin; fy1[k] = ymax;
                fwh[k] = wgt[k] / (ymax - ymin + TINY);
                fwv[k] = wgt[k] / (xmax - xmin + TINY);
                int ixl = min(max((int)(xmin * 0.5f), 0), NBX - 1);
                int ixh = min(min((int)(xmax * 0.5f) + 1, NBX), ixl + MAX_SPAN);
                int iyl = min(max((int)(ymin * 0.5f), 0), NBY - 1);
                int iyh = min(min((int)(ymax * 0.5f) + 1, NBY), iyl + MAX_SPAN);
                int txl = ixl >> TSB, txh = (ixh - 1) >> TSB;
                int tyl = iyl >> TSB, tyh = (iyh - 1) >> TSB;
                trng[k] = (u32)txl | ((u32)txh << 8) | ((u32)tyl << 16) | ((u32)tyh << 24);
                for (int tx = txl; tx <= txh; ++tx)
                    for (int ty = tyl; ty <= tyh; ++ty)
                        atomicAdd(&s_cnt[tx * NTT + ty], 1u);
            }
        }
    }
    __syncthreads();

    {
        u32 c = s_cnt[tid];
        u32 gbase = 0;
        if (c) gbase = atomicAdd(&cursor[((u32)tid * G + (u32)g) * CSTRIDE], c);
        s_cnt[tid] = gbase;
    }
    __syncthreads();

    #pragma unroll
    for (int k = 0; k < NPT; ++k) {
        u32 tr = trng[k];
        int txl = (int)(tr & 0xFFu), txh = (int)((tr >> 8) & 0xFFu);
        int tyl = (int)((tr >> 16) & 0xFFu), tyh = (int)(tr >> 24);
        for (int tx = txl; tx <= txh; ++tx) {
            float tox = (float)(tx << TSB) * BSX;
            float rx0 = fminf(fmaxf(fx0[k] - tox, 0.0f), 64.0f);
            float rx1 = fminf(fmaxf(fx1[k] - tox, 0.0f), 64.0f);
            u32 x0q = min((u32)(rx0 * 1024.0f + 0.5f), 65535u);
            u32 dxq = min((u32)((rx1 - rx0) * 16384.0f + 0.5f), 65535u);
            for (int ty = tyl; ty <= tyh; ++ty) {
                float toy = (float)(ty << TSB) * BSY;
                float ry0 = fminf(fmaxf(fy0[k] - toy, 0.0f), 64.0f);
                float ry1 = fminf(fmaxf(fy1[k] - toy, 0.0f), 64.0f);
                u32 y0q = min((u32)(ry0 * 1024.0f + 0.5f), 65535u);
                u32 dyq = min((u32)((ry1 - ry0) * 16384.0f + 0.5f), 65535u);
                int t = tx * NTT + ty;
                uint4 pk;
                pk.x = x0q | (dxq << 16);
                pk.y = y0q | (dyq << 16);
                pk.z = __float_as_uint(fwh[k]);
                pk.w = __float_as_uint(fwv[k]);
                u32 slot = atomicAdd(&s_fill[t], 1u);
                u32 pos = s_cnt[t] + slot;
                if (pos < (u32)SEG)
                    list[(((size_t)t * G + (size_t)g) << 10) + pos] = pk;
            }
        }
    }
}

__global__ __launch_bounds__(1024) void accum_tile(
    const uint4* __restrict__ list,
    const u32*   __restrict__ cursor,
    float*       __restrict__ out)
{
    __shared__ ull shv[TS * TS];

    int t = blockIdx.x;
    int tid = threadIdx.x;
    shv[tid] = 0ull;
    __syncthreads();

    u32 ng0 = min(cursor[((u32)t * G + 0) * CSTRIDE], (u32)SEG);
    u32 ng1 = min(cursor[((u32)t * G + 1) * CSTRIDE], (u32)SEG);
    u32 ng2 = min(cursor[((u32)t * G + 2) * CSTRIDE], (u32)SEG);
    u32 ng3 = min(cursor[((u32)t * G + 3) * CSTRIDE], (u32)SEG);
    u32 ng4 = min(cursor[((u32)t * G + 4) * CSTRIDE], (u32)SEG);
    u32 ng5 = min(cursor[((u32)t * G + 5) * CSTRIDE], (u32)SEG);
    u32 ng6 = min(cursor[((u32)t * G + 6) * CSTRIDE], (u32)SEG);
    u32 ng7 = min(cursor[((u32)t * G + 7) * CSTRIDE], (u32)SEG);

    const uint4* base = list + ((size_t)t * G << 10);

    uint4 t0, t1, t2, t3, t4, t5, t6, t7;
    if ((u32)tid < ng0) t0 = base[(0 << 10) + tid];
    if ((u32)tid < ng1) t1 = base[(1 << 10) + tid];
    if ((u32)tid < ng2) t2 = base[(2 << 10) + tid];
    if ((u32)tid < ng3) t3 = base[(3 << 10) + tid];
    if ((u32)tid < ng4) t4 = base[(4 << 10) + tid];
    if ((u32)tid < ng5) t5 = base[(5 << 10) + tid];
    if ((u32)tid < ng6) t6 = base[(6 << 10) + tid];
    if ((u32)tid < ng7) t7 = base[(7 << 10) + tid];

    PROCESS_ENTRY((u32)tid < ng0, t0, shv)
    PROCESS_ENTRY((u32)tid < ng1, t1, shv)
    PROCESS_ENTRY((u32)tid < ng2, t2, shv)
    PROCESS_ENTRY((u32)tid < ng3, t3, shv)
    PROCESS_ENTRY((u32)tid < ng4, t4, shv)
    PROCESS_ENTRY((u32)tid < ng5, t5, shv)
    PROCESS_ENTRY((u32)tid < ng6, t6, shv)
    PROCESS_ENTRY((u32)tid < ng7, t7, shv)

    __syncthreads();

    int tx = t >> 4, ty = t & 15;
    int bx = tid >> 5, by = tid & 31;
    ull p = shv[tid];
    float h = (float)(u32)(p >> 32);
    float v = (float)(u32)(p & 0xFFFFFFFFull);
    out[(size_t)(tx * TS + bx) * NBY + (ty * TS + by)] =
        fmaxf(h, v) * (FP_INV * (1.0f / 6.0f));
}

// ==================== fallback 2: r2 global-atomic path ====================

__global__ void rudy_accum_fb(const float* __restrict__ pin_pos,
                              const float* __restrict__ net_weights,
                              const int*   __restrict__ netpin_start,
                              const int*   __restrict__ flat_netpin,
                              ull*         __restrict__ hv,
                              int num_nets, int n_total)
{
    int i = blockIdx.x * blockDim.x + threadIdx.x;
    if (i >= num_nets) return;
    int s = netpin_start[i], e = netpin_start[i + 1];
    if (e <= s) return;
    float xmin = FLT_MAX, xmax = -FLT_MAX, ymin = FLT_MAX, ymax = -FLT_MAX;
    for (int p = s; p < e; ++p) {
        int idx = flat_netpin[p];
        float x = pin_pos[idx], y = pin_pos[idx + n_total];
        xmin = fminf(xmin, x); xmax = fmaxf(xmax, x);
        ymin = fminf(ymin, y); ymax = fmaxf(ymax, y);
    }
    int ixl = min(max((int)(xmin * 0.5f), 0), NBX - 1);
    int ixh = min((int)(xmax * 0.5f) + 1, NBX);
    int iyl = min(max((int)(ymin * 0.5f), 0), NBY - 1);
    int iyh = min((int)(ymax * 0.5f) + 1, NBY);
    float w = net_weights[i];
    float inv_h = 1.0f / (ymax - ymin + TINY);
    float inv_v = 1.0f / (xmax - xmin + TINY);
    #pragma unroll
    for (int dx = 0; dx < MAX_SPAN; ++dx) {
        int bx = ixl + dx;
        if (bx >= ixh) break;
        float bxl = (float)bx * BSX;
        float ox = fmaxf(fminf(xmax, bxl + BSX) - fmaxf(xmin, bxl), 0.0f);
        float wox = w * ox;
        #pragma unroll
        for (int dy = 0; dy < MAX_SPAN; ++dy) {
            int by = iyl + dy;
            if (by >= iyh) break;
            float byl = (float)by * BSY;
            float oy = fmaxf(fminf(ymax, byl + BSY) - fmaxf(ymin, byl), 0.0f);
            float ov = wox * oy;
            float hq = ov * inv_h * FP_SCALE + 0.5f;
            float vq = ov * inv_v * FP_SCALE + 0.5f;
            ull packed = ((ull)(unsigned int)hq << 32) | (ull)(unsigned int)vq;
            atomicAdd(&hv[bx * NBY + by], packed);
        }
    }
}

__global__ void rudy_final_fb(const ull* __restrict__ hv,
                              float* __restrict__ out, int n)
{
    int k = blockIdx.x * blockDim.x + threadIdx.x;
    if (k >= n) return;
    const float scale = FP_INV * (1.0f / 6.0f);
    ull p = hv[k];
    float h = (float)(unsigned int)(p >> 32) * scale;
    float v = (float)(unsigned int)(p & 0xFFFFFFFFull) * scale;
    out[k] = fmaxf(h, v);
}

// ============================ launcher ============================

extern "C" void kernel_launch(void* const* d_in, const int* in_sizes, int n_in,
                              void* d_out, int out_size, void* d_ws, size_t ws_size,
                              hipStream_t stream)
{
    const float* pin_pos      = (const float*)d_in[0];
    const float* net_weights  = (const float*)d_in[1];
    const int*   netpin_start = (const int*)d_in[2];
    const int*   flat_netpin  = (const int*)d_in[3];

    int num_nets = in_sizes[1];
    int n_total  = in_sizes[0] / 2;

    // ws layout: [cursor 256KB][partial 8MB][list 32MB]
    size_t off_partial = (size_t)NTILES * G * CSTRIDE * sizeof(u32);             // 256 KB
    size_t off_list    = off_partial + ((size_t)CBLK << 10) * sizeof(ull);       // +8 MB
    size_t need        = off_list + ((size_t)NTILES * G * SEG) * sizeof(uint4);  // +32 MB

    if (ws_size >= need) {
        u32*   cursor  = (u32*)d_ws;
        ull*   partial = (ull*)((char*)d_ws + off_partial);
        uint4* list    = (uint4*)((char*)d_ws + off_list);
        float* out     = (float*)d_out;

        // cooperative single-dispatch path (co-residency pre-check)
        int maxBlocksPerCU = 0;
        hipError_t eo = hipOccupancyMaxActiveBlocksPerMultiprocessor(
            &maxBlocksPerCU, rudy_fused, BTH, 0);
        bool coop_ok = (eo == hipSuccess) && (maxBlocksPerCU * 256 >= CBLK);

        if (coop_ok) {
            void* args[] = { (void*)&pin_pos, (void*)&net_weights,
                             (void*)&netpin_start, (void*)&flat_netpin,
                             (void*)&cursor, (void*)&list, (void*)&partial,
                             (void*)&out, (void*)&num_nets, (void*)&n_total };
            hipError_t el = hipLaunchCooperativeKernel(
                (void*)rudy_fused, dim3(CBLK), dim3(BTH), args, 0, stream);
            if (el == hipSuccess) return;
        }

        // fallback: r12 three-kernel path
        hipMemsetAsync(cursor, 0, off_partial, stream);
        int nb = (num_nets + NPB - 1) / NPB;
        bin_nets<<<nb, BTH, 0, stream>>>(pin_pos, net_weights,
                                         netpin_start, flat_netpin,
                                         cursor, list, num_nets, n_total);
        accum_tile<<<NTILES, 1024, 0, stream>>>(list, cursor, out);
    } else {
        // fallback 2: packed fixed-point global atomics
        ull* hv = (ull*)d_ws;
        hipMemsetAsync(hv, 0, (size_t)NBX * NBY * sizeof(ull), stream);
        int threads = 256;
        int blocks = (num_nets + threads - 1) / threads;
        rudy_accum_fb<<<blocks, threads, 0, stream>>>(pin_pos, net_weights,
                                                      netpin_start, flat_netpin,
                                                      hv, num_nets, n_total);
        int n = NBX * NBY;
        rudy_final_fb<<<(n + 255) / 256, 256, 0, stream>>>(hv, (float*)d_out, n);
    }
}

// Round 14
// 45.243 us; speedup vs baseline: 12.4529x; 12.4529x over previous
//
#include <hip/hip_runtime.h>
#include <float.h>

// Problem constants (match reference)
#define BSX 2.0f
#define BSY 2.0f
#define NBX 512
#define NBY 512
#define MAX_SPAN 4
#define TINY 1.17549435e-38f   // np.finfo(float32).tiny

// ---- Tiled path parameters ----
#define TSB 5                  // log2(tile size in bins): 32x32 bins = 64x64 units
#define TS  32
#define NTT 16                 // tiles per axis (512/32)
#define NTILES 256
#define BTH 256
#define NWV 4                  // waves per block
#define NPT 4                  // nets per thread
#define NPB (BTH * NPT)        // nets per block = 1024
#define CSTRIDE 32             // cursor padding: one 128B line per counter (r8: +7us)
#define G 8                    // cursor/list shards per tile
#define SEG 1024               // entries per (tile,shard) segment (mean ~537, +21 sigma)

#define FP_SCALE 4194304.0f    // 2^22 (validated r2/r5)
#define FP_INV   (1.0f / 4194304.0f)

typedef unsigned int u32;
typedef unsigned long long ull;

// Entry (16B): x: x0q(1/1024)|dxq(1/16384)<<16; y likewise; z/w: premult weights.

#define PROCESS_ENTRY(COND, PP, SHV)                                            \
    if (COND) {                                                                 \
        uint4 p = (PP);                                                         \
        float x0 = (float)(p.x & 0xFFFFu) * (1.0f / 1024.0f);                   \
        float x1 = x0 + (float)(p.x >> 16) * (1.0f / 16384.0f);                 \
        float y0 = (float)(p.y & 0xFFFFu) * (1.0f / 1024.0f);                   \
        float y1 = y0 + (float)(p.y >> 16) * (1.0f / 16384.0f);                 \
        float wh = __uint_as_float(p.z);                                        \
        float wv = __uint_as_float(p.w);                                        \
        int rxl = min((int)(x0 * 0.5f), TS - 1);                                \
        int rxh = min((int)(x1 * 0.5f) + 1, TS);                                \
        int ryl = min((int)(y0 * 0.5f), TS - 1);                                \
        int ryh = min((int)(y1 * 0.5f) + 1, TS);                                \
        for (int bx = rxl; bx < rxh; ++bx) {                                    \
            float bl = (float)bx * BSX;                                         \
            float ox = fmaxf(fminf(x1, bl + BSX) - fmaxf(x0, bl), 0.0f);        \
            float oxh = ox * wh * FP_SCALE, oxv = ox * wv * FP_SCALE;           \
            int rowbase = bx * TS;                                              \
            for (int by = ryl; by < ryh; ++by) {                                \
                float bb = (float)by * BSY;                                     \
                float oy = fmaxf(fminf(y1, bb + BSY) - fmaxf(y0, bb), 0.0f);    \
                u32 hq = (u32)(oxh * oy + 0.5f);                                \
                u32 vq = (u32)(oxv * oy + 0.5f);                                \
                ull pk = ((ull)hq << 32) | (ull)vq;                             \
                atomicAdd(&(SHV)[rowbase + by], pk);                            \
            }                                                                   \
        }                                                                       \
    }

// ============================ tiled path ============================

// count(slot-recording, wave-private) -> reserve -> direct-scatter emit.
__global__ __launch_bounds__(BTH, 4) void bin_nets(
    const float* __restrict__ pin_pos,
    const float* __restrict__ net_weights,
    const int*   __restrict__ netpin_start,
    const int*   __restrict__ flat_netpin,
    u32*         __restrict__ cursor,     // [NTILES*G] padded by CSTRIDE
    uint4*       __restrict__ list,       // [NTILES*G][SEG]
    int num_nets, int n_total)
{
    __shared__ u32 s_cnt[NWV * NTILES];   // wave-private counts -> per-wave bases (4 KB)

    int tid = threadIdx.x;
    int wv  = tid >> 6;                   // wave index 0..3
    int g = blockIdx.x & (G - 1);         // shard for this block
    #pragma unroll
    for (int j = 0; j < NWV; ++j) s_cnt[j * BTH + tid] = 0u;
    __syncthreads();

    int bs = blockIdx.x * NPB;

    // ---- phase-split loads: max memory-level parallelism ----
    int sA[NPT], eA[NPT];
    #pragma unroll
    for (int k = 0; k < NPT; ++k) {
        sA[k] = 0; eA[k] = 0;
        int i = bs + k * BTH + tid;
        if (i < num_nets) { sA[k] = netpin_start[i]; eA[k] = netpin_start[i + 1]; }
    }
    int4 fA[NPT];
    #pragma unroll
    for (int k = 0; k < NPT; ++k) {
        fA[k] = make_int4(-1, -1, -1, -1);
        if (eA[k] - sA[k] == 4 && (sA[k] & 3) == 0)
            fA[k] = *(const int4*)(flat_netpin + sA[k]);
    }
    bool idA[NPT];
    float4 xvA[NPT], yvA[NPT];
    #pragma unroll
    for (int k = 0; k < NPT; ++k) {
        int s = sA[k];
        idA[k] = (fA[k].x == s && fA[k].y == s + 1 && fA[k].z == s + 2 && fA[k].w == s + 3);
        if (idA[k]) {
            xvA[k] = *(const float4*)(pin_pos + s);
            yvA[k] = *(const float4*)(pin_pos + s + n_total);
        }
    }
    float wgt[NPT];
    #pragma unroll
    for (int k = 0; k < NPT; ++k) {
        int i = bs + k * BTH + tid;
        wgt[k] = (i < num_nets) ? net_weights[i] : 0.0f;
    }

    // ---- pass 1: bbox + wave-private counting, slots recorded in registers ----
    float fx0[NPT], fx1[NPT], fy0[NPT], fy1[NPT], fwh[NPT], fwv[NPT];
    u32 trng[NPT];          // txl | txh<<8 | tyl<<16 | tyh<<24 ; sentinel txl>txh
    u32 slotv[NPT * 4];     // static-indexed: [k*4 + jx*2 + jy]

    #pragma unroll
    for (int k = 0; k < NPT; ++k) {
        trng[k] = 0x00000001u;   // txl=1 > txh=0 -> all-invalid
        fx0[k] = 0.f; fx1[k] = 0.f; fy0[k] = 0.f; fy1[k] = 0.f;
        fwh[k] = 0.f; fwv[k] = 0.f;
        int i = bs + k * BTH + tid;
        if (i < num_nets) {
            bool have = false;
            float xmin, xmax, ymin, ymax;
            if (idA[k]) {
                xmin = fminf(fminf(xvA[k].x, xvA[k].y), fminf(xvA[k].z, xvA[k].w));
                xmax = fmaxf(fmaxf(xvA[k].x, xvA[k].y), fmaxf(xvA[k].z, xvA[k].w));
                ymin = fminf(fminf(yvA[k].x, yvA[k].y), fminf(yvA[k].z, yvA[k].w));
                ymax = fmaxf(fmaxf(yvA[k].x, yvA[k].y), fmaxf(yvA[k].z, yvA[k].w));
                have = true;
            } else if (eA[k] > sA[k]) {
                xmin = FLT_MAX; xmax = -FLT_MAX; ymin = FLT_MAX; ymax = -FLT_MAX;
                for (int p = sA[k]; p < eA[k]; ++p) {
                    int idx = flat_netpin[p];
                    float x = pin_pos[idx], y = pin_pos[idx + n_total];
                    xmin = fminf(xmin, x); xmax = fmaxf(xmax, x);
                    ymin = fminf(ymin, y); ymax = fmaxf(ymax, y);
                }
                have = true;
            }
            if (have) {
                fx0[k] = xmin; fx1[k] = xmax; fy0[k] = ymin; fy1[k] = ymax;
                fwh[k] = wgt[k] / (ymax - ymin + TINY);
                fwv[k] = wgt[k] / (xmax - xmin + TINY);
                int ixl = min(max((int)(xmin * 0.5f), 0), NBX - 1);
                int ixh = min(min((int)(xmax * 0.5f) + 1, NBX), ixl + MAX_SPAN);
                int iyl = min(max((int)(ymin * 0.5f), 0), NBY - 1);
                int iyh = min(min((int)(ymax * 0.5f) + 1, NBY), iyl + MAX_SPAN);
                int txl = ixl >> TSB, txh = (ixh - 1) >> TSB;
                int tyl = iyl >> TSB, tyh = (iyh - 1) >> TSB;
                trng[k] = (u32)txl | ((u32)txh << 8) | ((u32)tyl << 16) | ((u32)tyh << 24);
            }
        }
        // static 2x2 masked tile window; slot = pass-1 atomic return (wave-private)
        {
            u32 tr = trng[k];
            int txl = (int)(tr & 0xFFu), txh = (int)((tr >> 8) & 0xFFu);
            int tyl = (int)((tr >> 16) & 0xFFu), tyh = (int)(tr >> 24);
            #pragma unroll
            for (int jx = 0; jx < 2; ++jx) {
                int tx = txl + jx;
                bool vx = (tx <= txh);
                #pragma unroll
                for (int jy = 0; jy < 2; ++jy) {
                    int ty = tyl + jy;
                    slotv[k * 4 + jx * 2 + jy] = 0u;
                    if (vx && ty <= tyh)
                        slotv[k * 4 + jx * 2 + jy] =
                            atomicAdd(&s_cnt[wv * NTILES + tx * NTT + ty], 1u);
                }
            }
        }
    }
    __syncthreads();

    // ---- reserve: sum wave counts, one global atomic per touched tile,
    //      write back per-wave bases (all in LDS) ----
    {
        u32 c0 = s_cnt[0 * NTILES + tid];
        u32 c1 = s_cnt[1 * NTILES + tid];
        u32 c2 = s_cnt[2 * NTILES + tid];
        u32 c3 = s_cnt[3 * NTILES + tid];
        u32 tot = c0 + c1 + c2 + c3;
        u32 gb = 0;
        if (tot) gb = atomicAdd(&cursor[((u32)tid * G + (u32)g) * CSTRIDE], tot);
        s_cnt[0 * NTILES + tid] = gb;
        s_cnt[1 * NTILES + tid] = gb + c0;
        s_cnt[2 * NTILES + tid] = gb + c0 + c1;
        s_cnt[3 * NTILES + tid] = gb + c0 + c1 + c2;
    }
    __syncthreads();

    // ---- pass 2: emit using recorded slots (zero LDS atomics) ----
    #pragma unroll
    for (int k = 0; k < NPT; ++k) {
        u32 tr = trng[k];
        int txl = (int)(tr & 0xFFu), txh = (int)((tr >> 8) & 0xFFu);
        int tyl = (int)((tr >> 16) & 0xFFu), tyh = (int)(tr >> 24);
        #pragma unroll
        for (int jx = 0; jx < 2; ++jx) {
            int tx = txl + jx;
            bool vx = (tx <= txh);
            float tox = (float)(tx << TSB) * BSX;
            float rx0 = fminf(fmaxf(fx0[k] - tox, 0.0f), 64.0f);
            float rx1 = fminf(fmaxf(fx1[k] - tox, 0.0f), 64.0f);
            u32 x0q = min((u32)(rx0 * 1024.0f + 0.5f), 65535u);
            u32 dxq = min((u32)((rx1 - rx0) * 16384.0f + 0.5f), 65535u);
            #pragma unroll
            for (int jy = 0; jy < 2; ++jy) {
                int ty = tyl + jy;
                if (vx && ty <= tyh) {
                    float toy = (float)(ty << TSB) * BSY;
                    float ry0 = fminf(fmaxf(fy0[k] - toy, 0.0f), 64.0f);
                    float ry1 = fminf(fmaxf(fy1[k] - toy, 0.0f), 64.0f);
                    u32 y0q = min((u32)(ry0 * 1024.0f + 0.5f), 65535u);
                    u32 dyq = min((u32)((ry1 - ry0) * 16384.0f + 0.5f), 65535u);
                    int t = tx * NTT + ty;
                    u32 pos = s_cnt[wv * NTILES + t] + slotv[k * 4 + jx * 2 + jy];
                    if (pos < (u32)SEG) {
                        uint4 pk;
                        pk.x = x0q | (dxq << 16);
                        pk.y = y0q | (dyq << 16);
                        pk.z = __float_as_uint(fwh[k]);
                        pk.w = __float_as_uint(fwv[k]);
                        list[(((size_t)t * G + (size_t)g) << 10) + pos] = pk;
                    }
                }
            }
        }
    }
}

// One block per tile: thread tid owns slot tid of each of the tile's G segments.
__global__ __launch_bounds__(1024) void accum_tile(
    const uint4* __restrict__ list,
    const u32*   __restrict__ cursor,    // padded
    float*       __restrict__ out)
{
    __shared__ ull shv[TS * TS];

    int t = blockIdx.x;
    int tid = threadIdx.x;
    shv[tid] = 0ull;                     // 1024 threads == TS*TS
    __syncthreads();

    u32 ng0 = min(cursor[((u32)t * G + 0) * CSTRIDE], (u32)SEG);
    u32 ng1 = min(cursor[((u32)t * G + 1) * CSTRIDE], (u32)SEG);
    u32 ng2 = min(cursor[((u32)t * G + 2) * CSTRIDE], (u32)SEG);
    u32 ng3 = min(cursor[((u32)t * G + 3) * CSTRIDE], (u32)SEG);
    u32 ng4 = min(cursor[((u32)t * G + 4) * CSTRIDE], (u32)SEG);
    u32 ng5 = min(cursor[((u32)t * G + 5) * CSTRIDE], (u32)SEG);
    u32 ng6 = min(cursor[((u32)t * G + 6) * CSTRIDE], (u32)SEG);
    u32 ng7 = min(cursor[((u32)t * G + 7) * CSTRIDE], (u32)SEG);

    const uint4* base = list + ((size_t)t * G << 10);

    uint4 t0, t1, t2, t3, t4, t5, t6, t7;
    if ((u32)tid < ng0) t0 = base[(0 << 10) + tid];
    if ((u32)tid < ng1) t1 = base[(1 << 10) + tid];
    if ((u32)tid < ng2) t2 = base[(2 << 10) + tid];
    if ((u32)tid < ng3) t3 = base[(3 << 10) + tid];
    if ((u32)tid < ng4) t4 = base[(4 << 10) + tid];
    if ((u32)tid < ng5) t5 = base[(5 << 10) + tid];
    if ((u32)tid < ng6) t6 = base[(6 << 10) + tid];
    if ((u32)tid < ng7) t7 = base[(7 << 10) + tid];

    PROCESS_ENTRY((u32)tid < ng0, t0, shv)
    PROCESS_ENTRY((u32)tid < ng1, t1, shv)
    PROCESS_ENTRY((u32)tid < ng2, t2, shv)
    PROCESS_ENTRY((u32)tid < ng3, t3, shv)
    PROCESS_ENTRY((u32)tid < ng4, t4, shv)
    PROCESS_ENTRY((u32)tid < ng5, t5, shv)
    PROCESS_ENTRY((u32)tid < ng6, t6, shv)
    PROCESS_ENTRY((u32)tid < ng7, t7, shv)

    __syncthreads();

    int tx = t >> 4, ty = t & 15;
    int bx = tid >> 5, by = tid & 31;
    ull p = shv[tid];
    float h = (float)(u32)(p >> 32);
    float v = (float)(u32)(p & 0xFFFFFFFFull);
    out[(size_t)(tx * TS + bx) * NBY + (ty * TS + by)] =
        fmaxf(h, v) * (FP_INV * (1.0f / 6.0f));
}

// ======================= fallback path (round-2) =======================

__global__ void rudy_accum_fb(const float* __restrict__ pin_pos,
                              const float* __restrict__ net_weights,
                              const int*   __restrict__ netpin_start,
                              const int*   __restrict__ flat_netpin,
                              ull*         __restrict__ hv,
                              int num_nets, int n_total)
{
    int i = blockIdx.x * blockDim.x + threadIdx.x;
    if (i >= num_nets) return;
    int s = netpin_start[i], e = netpin_start[i + 1];
    if (e <= s) return;
    float xmin = FLT_MAX, xmax = -FLT_MAX, ymin = FLT_MAX, ymax = -FLT_MAX;
    for (int p = s; p < e; ++p) {
        int idx = flat_netpin[p];
        float x = pin_pos[idx], y = pin_pos[idx + n_total];
        xmin = fminf(xmin, x); xmax = fmaxf(xmax, x);
        ymin = fminf(ymin, y); ymax = fmaxf(ymax, y);
    }
    int ixl = min(max((int)(xmin * 0.5f), 0), NBX - 1);
    int ixh = min((int)(xmax * 0.5f) + 1, NBX);
    int iyl = min(max((int)(ymin * 0.5f), 0), NBY - 1);
    int iyh = min((int)(ymax * 0.5f) + 1, NBY);
    float w = net_weights[i];
    float inv_h = 1.0f / (ymax - ymin + TINY);
    float inv_v = 1.0f / (xmax - xmin + TINY);
    #pragma unroll
    for (int dx = 0; dx < MAX_SPAN; ++dx) {
        int bx = ixl + dx;
        if (bx >= ixh) break;
        float bxl = (float)bx * BSX;
        float ox = fmaxf(fminf(xmax, bxl + BSX) - fmaxf(xmin, bxl), 0.0f);
        float wox = w * ox;
        #pragma unroll
        for (int dy = 0; dy < MAX_SPAN; ++dy) {
            int by = iyl + dy;
            if (by >= iyh) break;
            float byl = (float)by * BSY;
            float oy = fmaxf(fminf(ymax, byl + BSY) - fmaxf(ymin, byl), 0.0f);
            float ov = wox * oy;
            float hq = ov * inv_h * FP_SCALE + 0.5f;
            float vq = ov * inv_v * FP_SCALE + 0.5f;
            ull packed = ((ull)(unsigned int)hq << 32) | (ull)(unsigned int)vq;
            atomicAdd(&hv[bx * NBY + by], packed);
        }
    }
}

__global__ void rudy_final_fb(const ull* __restrict__ hv,
                              float* __restrict__ out, int n)
{
    int k = blockIdx.x * blockDim.x + threadIdx.x;
    if (k >= n) return;
    const float scale = FP_INV * (1.0f / 6.0f);
    ull p = hv[k];
    float h = (float)(unsigned int)(p >> 32) * scale;
    float v = (float)(unsigned int)(p & 0xFFFFFFFFull) * scale;
    out[k] = fmaxf(h, v);
}

// ============================ launcher ============================

extern "C" void kernel_launch(void* const* d_in, const int* in_sizes, int n_in,
                              void* d_out, int out_size, void* d_ws, size_t ws_size,
                              hipStream_t stream)
{
    const float* pin_pos      = (const float*)d_in[0];
    const float* net_weights  = (const float*)d_in[1];
    const int*   netpin_start = (const int*)d_in[2];
    const int*   flat_netpin  = (const int*)d_in[3];

    int num_nets = in_sizes[1];
    int n_total  = in_sizes[0] / 2;

    // ws layout: [cursor 256KB][list: NTILES*G*SEG*16B = 32MB]
    size_t off_list = (size_t)NTILES * G * CSTRIDE * sizeof(u32);                 // 256 KB
    size_t need     = off_list + ((size_t)NTILES * G * SEG) * sizeof(uint4);      // +32 MB

    if (ws_size >= need) {
        u32*   cursor = (u32*)d_ws;
        uint4* list   = (uint4*)((char*)d_ws + off_list);

        hipMemsetAsync(cursor, 0, off_list, stream);

        int nb = (num_nets + NPB - 1) / NPB;
        bin_nets<<<nb, BTH, 0, stream>>>(pin_pos, net_weights,
                                         netpin_start, flat_netpin,
                                         cursor, list,
                                         num_nets, n_total);

        accum_tile<<<NTILES, 1024, 0, stream>>>(list, cursor, (float*)d_out);
    } else {
        // fallback: packed fixed-point global atomics
        ull* hv = (ull*)d_ws;
        hipMemsetAsync(hv, 0, (size_t)NBX * NBY * sizeof(ull), stream);
        int threads = 256;
        int blocks = (num_nets + threads - 1) / threads;
        rudy_accum_fb<<<blocks, threads, 0, stream>>>(pin_pos, net_weights,
                                                      netpin_start, flat_netpin,
                                                      hv, num_nets, n_total);
        int n = NBX * NBY;
        rudy_final_fb<<<(n + 255) / 256, 256, 0, stream>>>(hv, (float*)d_out, n);
    }
}

// Round 16
// 43.908 us; speedup vs baseline: 12.8315x; 1.0304x over previous
//
#include <hip/hip_runtime.h>
#include <float.h>

// Problem constants (match reference)
#define BSX 2.0f
#define BSY 2.0f
#define NBX 512
#define NBY 512
#define MAX_SPAN 4
#define TINY 1.17549435e-38f   // np.finfo(float32).tiny

// ---- Tiled path parameters ----
#define TSB 5                  // log2(tile size in bins): 32x32 bins = 64x64 units
#define TS  32
#define NTT 16                 // tiles per axis (512/32)
#define NTILES 256
#define BTH 256
#define NWV 4                  // waves per block
#define NPT 4                  // nets per thread
#define NPB (BTH * NPT)        // nets per block = 1024
#define ECAP 2048              // per-block staging/region capacity (mean ~1126, +60 sigma)

#define FP_SCALE 4194304.0f    // 2^22 (validated r2/r5)
#define FP_INV   (1.0f / 4194304.0f)

typedef unsigned int u32;
typedef unsigned long long ull;

// Entry (16B): x: x0q(1/1024)|dxq(1/16384)<<16; y likewise; z/w: premult weights.
// dir[b][t] = base | (visible_count << 16)  (base,count < 65536)

// NOTE: internal var renamed _e to avoid shadowing any caller argument (r15 bug:
// PROCESS_ENTRY(true, p, ..) expanded to `uint4 p = (p);` -- self-init undef).
#define PROCESS_ENTRY(COND, PP, SHV)                                            \
    if (COND) {                                                                 \
        uint4 _e = (PP);                                                        \
        float x0 = (float)(_e.x & 0xFFFFu) * (1.0f / 1024.0f);                  \
        float x1 = x0 + (float)(_e.x >> 16) * (1.0f / 16384.0f);                \
        float y0 = (float)(_e.y & 0xFFFFu) * (1.0f / 1024.0f);                  \
        float y1 = y0 + (float)(_e.y >> 16) * (1.0f / 16384.0f);                \
        float wh = __uint_as_float(_e.z);                                       \
        float wv = __uint_as_float(_e.w);                                       \
        int rxl = min((int)(x0 * 0.5f), TS - 1);                                \
        int rxh = min((int)(x1 * 0.5f) + 1, TS);                                \
        int ryl = min((int)(y0 * 0.5f), TS - 1);                                \
        int ryh = min((int)(y1 * 0.5f) + 1, TS);                                \
        for (int bx = rxl; bx < rxh; ++bx) {                                    \
            float bl = (float)bx * BSX;                                         \
            float ox = fmaxf(fminf(x1, bl + BSX) - fmaxf(x0, bl), 0.0f);        \
            float oxh = ox * wh * FP_SCALE, oxv = ox * wv * FP_SCALE;           \
            int rowbase = bx * TS;                                              \
            for (int by = ryl; by < ryh; ++by) {                                \
                float bb = (float)by * BSY;                                     \
                float oy = fmaxf(fminf(y1, bb + BSY) - fmaxf(y0, bb), 0.0f);    \
                u32 hq = (u32)(oxh * oy + 0.5f);                                \
                u32 vq = (u32)(oxv * oy + 0.5f);                                \
                ull pk = ((ull)hq << 32) | (ull)vq;                             \
                atomicAdd(&(SHV)[rowbase + by], pk);                            \
            }                                                                   \
        }                                                                       \
    }

// ============================ tiled path ============================
// Zero cross-block coordination: no cursors, no global atomics, no memset.
// Block b: count (wave-private) -> local scan -> tile-sorted LDS staging ->
// coalesced dump to private region + directory write.

__global__ __launch_bounds__(BTH, 4) void bin_nets(
    const float* __restrict__ pin_pos,
    const float* __restrict__ net_weights,
    const int*   __restrict__ netpin_start,
    const int*   __restrict__ flat_netpin,
    u32*         __restrict__ dir,        // [nb][NTILES]
    uint4*       __restrict__ list,       // [nb][ECAP]
    int num_nets, int n_total)
{
    __shared__ u32 s_cnt[NWV * NTILES];   // wave-private counts -> per-wave bases (4 KB)
    __shared__ u32 s_wsum[NWV];
    __shared__ uint4 s_ent[ECAP];         // 32 KB tile-sorted staging

    int tid = threadIdx.x;
    int wvi = tid >> 6;                   // wave index 0..3
    int b = blockIdx.x;
    #pragma unroll
    for (int j = 0; j < NWV; ++j) s_cnt[j * BTH + tid] = 0u;
    __syncthreads();

    int bs = b * NPB;

    // ---- phase-split loads: max memory-level parallelism ----
    int sA[NPT], eA[NPT];
    #pragma unroll
    for (int k = 0; k < NPT; ++k) {
        sA[k] = 0; eA[k] = 0;
        int i = bs + k * BTH + tid;
        if (i < num_nets) { sA[k] = netpin_start[i]; eA[k] = netpin_start[i + 1]; }
    }
    int4 fA[NPT];
    #pragma unroll
    for (int k = 0; k < NPT; ++k) {
        fA[k] = make_int4(-1, -1, -1, -1);
        if (eA[k] - sA[k] == 4 && (sA[k] & 3) == 0)
            fA[k] = *(const int4*)(flat_netpin + sA[k]);
    }
    bool idA[NPT];
    float4 xvA[NPT], yvA[NPT];
    #pragma unroll
    for (int k = 0; k < NPT; ++k) {
        int s = sA[k];
        idA[k] = (fA[k].x == s && fA[k].y == s + 1 && fA[k].z == s + 2 && fA[k].w == s + 3);
        if (idA[k]) {
            xvA[k] = *(const float4*)(pin_pos + s);
            yvA[k] = *(const float4*)(pin_pos + s + n_total);
        }
    }
    float wgt[NPT];
    #pragma unroll
    for (int k = 0; k < NPT; ++k) {
        int i = bs + k * BTH + tid;
        wgt[k] = (i < num_nets) ? net_weights[i] : 0.0f;
    }

    // ---- pass 1: bbox + wave-private counting, slots recorded in registers ----
    float fx0[NPT], fx1[NPT], fy0[NPT], fy1[NPT], fwh[NPT], fwv[NPT];
    u32 trng[NPT];          // txl | txh<<8 | tyl<<16 | tyh<<24 ; sentinel txl>txh
    u32 slotv[NPT * 4];     // static-indexed: [k*4 + jx*2 + jy]

    #pragma unroll
    for (int k = 0; k < NPT; ++k) {
        trng[k] = 0x00000001u;   // txl=1 > txh=0 -> all-invalid
        fx0[k] = 0.f; fx1[k] = 0.f; fy0[k] = 0.f; fy1[k] = 0.f;
        fwh[k] = 0.f; fwv[k] = 0.f;
        int i = bs + k * BTH + tid;
        if (i < num_nets) {
            bool have = false;
            float xmin, xmax, ymin, ymax;
            if (idA[k]) {
                xmin = fminf(fminf(xvA[k].x, xvA[k].y), fminf(xvA[k].z, xvA[k].w));
                xmax = fmaxf(fmaxf(xvA[k].x, xvA[k].y), fmaxf(xvA[k].z, xvA[k].w));
                ymin = fminf(fminf(yvA[k].x, yvA[k].y), fminf(yvA[k].z, yvA[k].w));
                ymax = fmaxf(fmaxf(yvA[k].x, yvA[k].y), fmaxf(yvA[k].z, yvA[k].w));
                have = true;
            } else if (eA[k] > sA[k]) {
                xmin = FLT_MAX; xmax = -FLT_MAX; ymin = FLT_MAX; ymax = -FLT_MAX;
                for (int p = sA[k]; p < eA[k]; ++p) {
                    int idx = flat_netpin[p];
                    float x = pin_pos[idx], y = pin_pos[idx + n_total];
                    xmin = fminf(xmin, x); xmax = fmaxf(xmax, x);
                    ymin = fminf(ymin, y); ymax = fmaxf(ymax, y);
                }
                have = true;
            }
            if (have) {
                fx0[k] = xmin; fx1[k] = xmax; fy0[k] = ymin; fy1[k] = ymax;
                fwh[k] = wgt[k] / (ymax - ymin + TINY);
                fwv[k] = wgt[k] / (xmax - xmin + TINY);
                int ixl = min(max((int)(xmin * 0.5f), 0), NBX - 1);
                int ixh = min(min((int)(xmax * 0.5f) + 1, NBX), ixl + MAX_SPAN);
                int iyl = min(max((int)(ymin * 0.5f), 0), NBY - 1);
                int iyh = min(min((int)(ymax * 0.5f) + 1, NBY), iyl + MAX_SPAN);
                int txl = ixl >> TSB, txh = (ixh - 1) >> TSB;
                int tyl = iyl >> TSB, tyh = (iyh - 1) >> TSB;
                trng[k] = (u32)txl | ((u32)txh << 8) | ((u32)tyl << 16) | ((u32)tyh << 24);
            }
        }
        // static 2x2 masked tile window; slot = wave-private atomic return
        {
            u32 tr = trng[k];
            int txl = (int)(tr & 0xFFu), txh = (int)((tr >> 8) & 0xFFu);
            int tyl = (int)((tr >> 16) & 0xFFu), tyh = (int)(tr >> 24);
            #pragma unroll
            for (int jx = 0; jx < 2; ++jx) {
                int tx = txl + jx;
                bool vx = (tx <= txh);
                #pragma unroll
                for (int jy = 0; jy < 2; ++jy) {
                    int ty = tyl + jy;
                    slotv[k * 4 + jx * 2 + jy] = 0u;
                    if (vx && ty <= tyh)
                        slotv[k * 4 + jx * 2 + jy] =
                            atomicAdd(&s_cnt[wvi * NTILES + tx * NTT + ty], 1u);
                }
            }
        }
    }
    __syncthreads();

    // ---- local scan: per-tile exclusive bases (no global atomics) ----
    u32 c0 = s_cnt[0 * NTILES + tid];
    u32 c1 = s_cnt[1 * NTILES + tid];
    u32 c2 = s_cnt[2 * NTILES + tid];
    u32 c3 = s_cnt[3 * NTILES + tid];
    u32 cnt = c0 + c1 + c2 + c3;          // this tile's total (tile == tid)
    {
        u32 v = cnt;
        int lane = tid & 63;
        #pragma unroll
        for (int d = 1; d < 64; d <<= 1) {
            u32 o = __shfl_up(v, d);
            if (lane >= d) v += o;
        }
        if (lane == 63) s_wsum[wvi] = v;
        __syncthreads();
        u32 woff = 0;
        #pragma unroll
        for (int j = 0; j < NWV; ++j) {
            u32 sj = s_wsum[j];
            if (j < wvi) woff += sj;
        }
        u32 base = woff + v - cnt;        // exclusive base for tile tid
        // per-wave staging bases
        s_cnt[0 * NTILES + tid] = base;
        s_cnt[1 * NTILES + tid] = base + c0;
        s_cnt[2 * NTILES + tid] = base + c0 + c1;
        s_cnt[3 * NTILES + tid] = base + c0 + c1 + c2;
        // write directory now (registers): visible count clamped to ECAP
        u32 vis = (base >= (u32)ECAP) ? 0u
                  : min(cnt, (u32)ECAP - base);
        dir[(size_t)b * NTILES + (u32)tid] = base | (vis << 16);
    }
    __syncthreads();

    // ---- pass 2: stage entries tile-sorted into LDS (zero LDS atomics) ----
    #pragma unroll
    for (int k = 0; k < NPT; ++k) {
        u32 tr = trng[k];
        int txl = (int)(tr & 0xFFu), txh = (int)((tr >> 8) & 0xFFu);
        int tyl = (int)((tr >> 16) & 0xFFu), tyh = (int)(tr >> 24);
        #pragma unroll
        for (int jx = 0; jx < 2; ++jx) {
            int tx = txl + jx;
            bool vx = (tx <= txh);
            float tox = (float)(tx << TSB) * BSX;
            float rx0 = fminf(fmaxf(fx0[k] - tox, 0.0f), 64.0f);
            float rx1 = fminf(fmaxf(fx1[k] - tox, 0.0f), 64.0f);
            u32 x0q = min((u32)(rx0 * 1024.0f + 0.5f), 65535u);
            u32 dxq = min((u32)((rx1 - rx0) * 16384.0f + 0.5f), 65535u);
            #pragma unroll
            for (int jy = 0; jy < 2; ++jy) {
                int ty = tyl + jy;
                if (vx && ty <= tyh) {
                    float toy = (float)(ty << TSB) * BSY;
                    float ry0 = fminf(fmaxf(fy0[k] - toy, 0.0f), 64.0f);
                    float ry1 = fminf(fmaxf(fy1[k] - toy, 0.0f), 64.0f);
                    u32 y0q = min((u32)(ry0 * 1024.0f + 0.5f), 65535u);
                    u32 dyq = min((u32)((ry1 - ry0) * 16384.0f + 0.5f), 65535u);
                    int t = tx * NTT + ty;
                    u32 idx = s_cnt[wvi * NTILES + t] + slotv[k * 4 + jx * 2 + jy];
                    if (idx < (u32)ECAP) {
                        uint4 pk;
                        pk.x = x0q | (dxq << 16);
                        pk.y = y0q | (dyq << 16);
                        pk.z = __float_as_uint(fwh[k]);
                        pk.w = __float_as_uint(fwv[k]);
                        s_ent[idx] = pk;
                    }
                }
            }
        }
    }
    __syncthreads();

    // ---- coalesced dump of the tile-sorted staging to the private region ----
    u32 E = s_wsum[0] + s_wsum[1] + s_wsum[2] + s_wsum[3];
    if (E > (u32)ECAP) E = (u32)ECAP;
    uint4* reg = list + (size_t)b * ECAP;
    for (u32 e = tid; e < E; e += BTH) reg[e] = s_ent[e];
}

// One block per tile: thread j walks block j's run via the directory.
__global__ __launch_bounds__(1024) void accum_tile(
    const uint4* __restrict__ list,
    const u32*   __restrict__ dir,
    int nb,
    float*       __restrict__ out)
{
    __shared__ ull shv[TS * TS];

    int t = blockIdx.x;
    int tid = threadIdx.x;
    shv[tid] = 0ull;                     // 1024 threads == TS*TS
    __syncthreads();

    for (int j = tid; j < nb; j += 1024) {
        u32 d = dir[(size_t)j * NTILES + t];
        u32 off = d & 0xFFFFu;
        u32 cnt = d >> 16;
        const uint4* run = list + (size_t)j * ECAP + off;
        for (u32 c = 0; c < cnt; ++c) {
            uint4 ent = run[c];
            PROCESS_ENTRY(true, ent, shv)
        }
    }
    __syncthreads();

    int tx = t >> 4, ty = t & 15;
    int bx = tid >> 5, by = tid & 31;
    ull p = shv[tid];
    float h = (float)(u32)(p >> 32);
    float v = (float)(u32)(p & 0xFFFFFFFFull);
    out[(size_t)(tx * TS + bx) * NBY + (ty * TS + by)] =
        fmaxf(h, v) * (FP_INV * (1.0f / 6.0f));
}

// ======================= fallback path (round-2) =======================

__global__ void rudy_accum_fb(const float* __restrict__ pin_pos,
                              const float* __restrict__ net_weights,
                              const int*   __restrict__ netpin_start,
                              const int*   __restrict__ flat_netpin,
                              ull*         __restrict__ hv,
                              int num_nets, int n_total)
{
    int i = blockIdx.x * blockDim.x + threadIdx.x;
    if (i >= num_nets) return;
    int s = netpin_start[i], e = netpin_start[i + 1];
    if (e <= s) return;
    float xmin = FLT_MAX, xmax = -FLT_MAX, ymin = FLT_MAX, ymax = -FLT_MAX;
    for (int p = s; p < e; ++p) {
        int idx = flat_netpin[p];
        float x = pin_pos[idx], y = pin_pos[idx + n_total];
        xmin = fminf(xmin, x); xmax = fmaxf(xmax, x);
        ymin = fminf(ymin, y); ymax = fmaxf(ymax, y);
    }
    int ixl = min(max((int)(xmin * 0.5f), 0), NBX - 1);
    int ixh = min((int)(xmax * 0.5f) + 1, NBX);
    int iyl = min(max((int)(ymin * 0.5f), 0), NBY - 1);
    int iyh = min((int)(ymax * 0.5f) + 1, NBY);
    float w = net_weights[i];
    float inv_h = 1.0f / (ymax - ymin + TINY);
    float inv_v = 1.0f / (xmax - xmin + TINY);
    #pragma unroll
    for (int dx = 0; dx < MAX_SPAN; ++dx) {
        int bx = ixl + dx;
        if (bx >= ixh) break;
        float bxl = (float)bx * BSX;
        float ox = fmaxf(fminf(xmax, bxl + BSX) - fmaxf(xmin, bxl), 0.0f);
        float wox = w * ox;
        #pragma unroll
        for (int dy = 0; dy < MAX_SPAN; ++dy) {
            int by = iyl + dy;
            if (by >= iyh) break;
            float byl = (float)by * BSY;
            float oy = fmaxf(fminf(ymax, byl + BSY) - fmaxf(ymin, byl), 0.0f);
            float ov = wox * oy;
            float hq = ov * inv_h * FP_SCALE + 0.5f;
            float vq = ov * inv_v * FP_SCALE + 0.5f;
            ull packed = ((ull)(unsigned int)hq << 32) | (ull)(unsigned int)vq;
            atomicAdd(&hv[bx * NBY + by], packed);
        }
    }
}

__global__ void rudy_final_fb(const ull* __restrict__ hv,
                              float* __restrict__ out, int n)
{
    int k = blockIdx.x * blockDim.x + threadIdx.x;
    if (k >= n) return;
    const float scale = FP_INV * (1.0f / 6.0f);
    ull p = hv[k];
    float h = (float)(unsigned int)(p >> 32) * scale;
    float v = (float)(unsigned int)(p & 0xFFFFFFFFull) * scale;
    out[k] = fmaxf(h, v);
}

// ============================ launcher ============================

extern "C" void kernel_launch(void* const* d_in, const int* in_sizes, int n_in,
                              void* d_out, int out_size, void* d_ws, size_t ws_size,
                              hipStream_t stream)
{
    const float* pin_pos      = (const float*)d_in[0];
    const float* net_weights  = (const float*)d_in[1];
    const int*   netpin_start = (const int*)d_in[2];
    const int*   flat_netpin  = (const int*)d_in[3];

    int num_nets = in_sizes[1];
    int n_total  = in_sizes[0] / 2;

    int nb = (num_nets + NPB - 1) / NPB;

    // ws layout: [dir nb*1KB][list nb*32KB] -- no initialization needed at all
    size_t dir_bytes = (size_t)nb * NTILES * sizeof(u32);
    size_t off_list  = (dir_bytes + 4095) & ~(size_t)4095;
    size_t need      = off_list + (size_t)nb * ECAP * sizeof(uint4);

    if (ws_size >= need && nb <= 65535) {
        u32*   dir  = (u32*)d_ws;
        uint4* list = (uint4*)((char*)d_ws + off_list);

        bin_nets<<<nb, BTH, 0, stream>>>(pin_pos, net_weights,
                                         netpin_start, flat_netpin,
                                         dir, list, num_nets, n_total);

        accum_tile<<<NTILES, 1024, 0, stream>>>(list, dir, nb, (float*)d_out);
    } else {
        // fallback: packed fixed-point global atomics
        ull* hv = (ull*)d_ws;
        hipMemsetAsync(hv, 0, (size_t)NBX * NBY * sizeof(ull), stream);
        int threads = 256;
        int blocks = (num_nets + threads - 1) / threads;
        rudy_accum_fb<<<blocks, threads, 0, stream>>>(pin_pos, net_weights,
                                                      netpin_start, flat_netpin,
                                                      hv, num_nets, n_total);
        int n = NBX * NBY;
        rudy_final_fb<<<(n + 255) / 256, 256, 0, stream>>>(hv, (float*)d_out, n);
    }
}